// Round 1
// baseline (259.642 us; speedup 1.0000x reference)
//
#include <hip/hip_runtime.h>
#include <math.h>

// Problem constants (fixed by the reference): ip (8, 256, 128, 128) fp32.
#define NB   8
#define NC   256
#define NHW  (128 * 128)

// GEMM tiling: block tile 128(c) x 64(p), K-step 32, 256 threads = 4 waves (2x2),
// wave tile 64(c) x 32(p) -> acc = 32 regs/lane (keeps VGPR+AGPR <= 128 -> 4 blocks/CU).
#define BM 128
#define BN 64
#define BK 32
#define NITER (NC / BK)   // 8

typedef __attribute__((ext_vector_type(4))) float f32x4;
typedef __attribute__((ext_vector_type(8))) short bf16x8;

__device__ __forceinline__ unsigned short f2bf(float f) {
    unsigned u = __builtin_bit_cast(unsigned, f);
    u += 0x7fffu + ((u >> 16) & 1u);
    return (unsigned short)(u >> 16);
}

__device__ __forceinline__ unsigned pack2bf(float a, float b) {
    unsigned lo = __builtin_bit_cast(unsigned, a);
    lo += 0x7fffu + ((lo >> 16) & 1u);
    unsigned hi = __builtin_bit_cast(unsigned, b);
    hi += 0x7fffu + ((hi >> 16) & 1u);
    return (lo >> 16) | (hi & 0xffff0000u);
}

// Kernel 1: DCT-III coefficient matrix, bf16, row-major [c][k], 256x256.
// M[c][k] = (k==0) ? 1 : 2*cos(pi*k*(2c+1)/512).
__global__ void coef_kernel(unsigned short* __restrict__ coef) {
    int idx = blockIdx.x * 256 + threadIdx.x;     // 0..65535
    int c = idx >> 8;
    int k = idx & 255;
    int t = (k * (2 * c + 1)) & 1023;
    float v = (k == 0) ? 1.0f : 2.0f * cosf((float)t * (float)(M_PI / 512.0));
    coef[idx] = f2bf(v);
}

__device__ __forceinline__ void gload_lds16(const void* g, void* l) {
    __builtin_amdgcn_global_load_lds(
        (const __attribute__((address_space(1))) unsigned int*)g,
        (__attribute__((address_space(3))) unsigned int*)l,
        16, 0, 0);
}

// LDS layout (linear rows of 64 B = 32 bf16 per row):
//   A dbuf: [0, 8192) and [8192, 16384)    (128 rows x 64 B)
//   X dbuf: [16384, 20480) and [20480, 24576) (64 rows x 64 B)
// Swizzle: logical 16-B quad q of row r lives at slot (q ^ ((r>>1)&3)).
// -> any 16-lane frag read / 64-lane stage write hits each bank-quad exactly 2x (free).

__global__ __launch_bounds__(256, 4)
void dct_gemm(const float* __restrict__ X, const unsigned short* __restrict__ Mcoef,
              float* __restrict__ Out) {
    __shared__ __align__(16) unsigned char lds[24576];

    const int tid  = threadIdx.x;
    const int lane = tid & 63;
    const int wave = tid >> 6;
    const int m16  = lane & 15;
    const int quad = lane >> 4;
    const int wm   = wave >> 1;       // c-half (64)
    const int wn   = wave & 1;        // p-half (32)

    const int p0 = blockIdx.x * BN;
    const int c0 = blockIdx.y * BM;
    const size_t bbase = (size_t)blockIdx.z * (NC * NHW);
    const float* Xg = X + bbase;
    float* Og = Out + bbase;

    // ---- A staging via global_load_lds: linear LDS dest, pre-swizzled global source ----
    // wave w, instr j covers LDS bytes [w*2048 + j*1024, +1024), lane offset = lane*16.
    const int bA0 = wave * 2048 + lane * 16;
    const int bA1 = bA0 + 1024;
    const int rA0 = bA0 >> 6, rA1 = bA1 >> 6;
    const int qA0 = ((bA0 >> 4) & 3) ^ ((rA0 >> 1) & 3);   // logical quad stored at this slot
    const int qA1 = ((bA1 >> 4) & 3) ^ ((rA1 >> 1) & 3);
    const unsigned short* aSrc0 = Mcoef + (c0 + rA0) * NC + qA0 * 8;
    const unsigned short* aSrc1 = Mcoef + (c0 + rA1) * NC + qA1 * 8;

    // ---- X staging roles: p-row = lane, k-chunk of 8 = wave ----
    const int sp = lane;
    const float* xSrc = Xg + (size_t)(wave * 8) * NHW + p0 + sp;
    const int xWoff = sp * 64 + ((wave ^ ((sp >> 1) & 3)) << 4);  // swizzled b128 write slot

    // ---- loop-invariant fragment byte offsets (swizzled reads) ----
    int offA[4], offB[2];
#pragma unroll
    for (int mt = 0; mt < 4; mt++) {
        int r = wm * 64 + mt * 16 + m16;
        offA[mt] = r * 64 + ((quad ^ ((r >> 1) & 3)) << 4);
    }
#pragma unroll
    for (int nt = 0; nt < 2; nt++) {
        int r = wn * 32 + nt * 16 + m16;
        offB[nt] = r * 64 + ((quad ^ ((r >> 1) & 3)) << 4);
    }

    f32x4 acc[4][2];
#pragma unroll
    for (int i = 0; i < 4; i++)
#pragma unroll
        for (int j = 0; j < 2; j++) acc[i][j] = (f32x4){0.f, 0.f, 0.f, 0.f};

    // ---- prologue: stage tile 0 into buffer 0 ----
    {
        float xv[8];
#pragma unroll
        for (int j = 0; j < 8; j++) xv[j] = xSrc[(size_t)j * NHW];  // coalesced: 64 lanes = 256 B
        gload_lds16(aSrc0, lds + 0 + bA0);
        gload_lds16(aSrc1, lds + 0 + bA1);
        int4 w = { (int)pack2bf(xv[0], xv[1]), (int)pack2bf(xv[2], xv[3]),
                   (int)pack2bf(xv[4], xv[5]), (int)pack2bf(xv[6], xv[7]) };
        *(int4*)(lds + 16384 + xWoff) = w;
    }
    __syncthreads();

    // ---- main loop: 1 barrier per k-step, depth-1 prefetch ----
#pragma unroll
    for (int t = 0; t < NITER; t++) {
        const int cb = t & 1;                         // compute buffer
        const unsigned char* Ac = lds + (cb ? 8192 : 0);
        const unsigned char* Xc = lds + 16384 + (cb ? 4096 : 0);
        unsigned char* As = lds + (cb ? 0 : 8192);    // stage buffer (other)
        unsigned char* Xs = lds + 16384 + (cb ? 0 : 4096);

        float xv[8];
        if (t + 1 < NITER) {
            const int k0 = (t + 1) * BK;
            // issue X reg-loads first (so the later wait leaves A gloads in flight),
            // then async A global->LDS. Latency hides under the MFMA phase below.
#pragma unroll
            for (int j = 0; j < 8; j++) xv[j] = xSrc[(size_t)(k0 + j) * NHW];
            gload_lds16(aSrc0 + k0, As + bA0);
            gload_lds16(aSrc1 + k0, As + bA1);
        }

        bf16x8 af[4], bfr[2];
#pragma unroll
        for (int mt = 0; mt < 4; mt++) af[mt] = *(const bf16x8*)(Ac + offA[mt]);
#pragma unroll
        for (int nt = 0; nt < 2; nt++) bfr[nt] = *(const bf16x8*)(Xc + offB[nt]);
#pragma unroll
        for (int mt = 0; mt < 4; mt++)
#pragma unroll
            for (int nt = 0; nt < 2; nt++)
                acc[mt][nt] = __builtin_amdgcn_mfma_f32_16x16x32_bf16(
                    af[mt], bfr[nt], acc[mt][nt], 0, 0, 0);

        if (t + 1 < NITER) {
            int4 w = { (int)pack2bf(xv[0], xv[1]), (int)pack2bf(xv[2], xv[3]),
                       (int)pack2bf(xv[4], xv[5]), (int)pack2bf(xv[6], xv[7]) };
            *(int4*)(Xs + xWoff) = w;
            __syncthreads();   // drains gload_lds (vmcnt0) + makes ds_write visible
        }
    }

    // ---- epilogue: D layout col = lane&15 (p), row = quad*4 + r (c) ----
#pragma unroll
    for (int mt = 0; mt < 4; mt++) {
        const int cc = c0 + wm * 64 + mt * 16 + quad * 4;
#pragma unroll
        for (int nt = 0; nt < 2; nt++) {
            const int pp = p0 + wn * 32 + nt * 16 + m16;
            float* o = Og + (size_t)cc * NHW + pp;
#pragma unroll
            for (int r = 0; r < 4; r++)
                __builtin_nontemporal_store(acc[mt][nt][r], o + (size_t)r * NHW);
        }
    }
}

extern "C" void kernel_launch(void* const* d_in, const int* in_sizes, int n_in,
                              void* d_out, int out_size, void* d_ws, size_t ws_size,
                              hipStream_t stream) {
    const float* ip = (const float*)d_in[0];
    float* out = (float*)d_out;
    unsigned short* coef = (unsigned short*)d_ws;   // 256*256*2 = 128 KB of scratch

    // must redo every launch: d_ws is re-poisoned before each timed call
    coef_kernel<<<dim3(256), dim3(256), 0, stream>>>(coef);

    dim3 grid(NHW / BN, NC / BM, NB);   // (256, 2, 8)
    dct_gemm<<<grid, dim3(256), 0, stream>>>(ip, coef, out);
}

// Round 2
// 235.170 us; speedup vs baseline: 1.1041x; 1.1041x over previous
//
#include <hip/hip_runtime.h>
#include <math.h>

// Problem constants (fixed by the reference): ip (8, 256, 128, 128) fp32.
#define NB   8
#define NC   256
#define NHW  (128 * 128)

// GEMM tiling: block tile 256(c) x 64(p) -> X read exactly ONCE from global.
// 512 threads = 8 waves (4x2), wave tile 64(c) x 32(p) -> acc = 32 regs/lane.
// BK=64 -> 4 k-steps, LDS = 2*(256*128 + 64*128) = 80 KB -> 2 blocks/CU.
#define BM 256
#define BN 64
#define BK 64
#define NITER (NC / BK)   // 4

// LDS map (byte offsets): A dbuf [0,32768)+[32768,65536); X dbuf [65536,73728)+[73728,81920)
#define XBASE 65536

typedef __attribute__((ext_vector_type(4))) float f32x4;
typedef __attribute__((ext_vector_type(8))) short bf16x8;

__device__ __forceinline__ unsigned short f2bf(float f) {
    unsigned u = __builtin_bit_cast(unsigned, f);
    u += 0x7fffu + ((u >> 16) & 1u);
    return (unsigned short)(u >> 16);
}

__device__ __forceinline__ unsigned pack2bf(float a, float b) {
    unsigned lo = __builtin_bit_cast(unsigned, a);
    lo += 0x7fffu + ((lo >> 16) & 1u);
    unsigned hi = __builtin_bit_cast(unsigned, b);
    hi += 0x7fffu + ((hi >> 16) & 1u);
    return (lo >> 16) | (hi & 0xffff0000u);
}

// Kernel 1: DCT-III coefficient matrix, bf16, row-major [c][k], 256x256.
__global__ void coef_kernel(unsigned short* __restrict__ coef) {
    int idx = blockIdx.x * 256 + threadIdx.x;     // 0..65535
    int c = idx >> 8;
    int k = idx & 255;
    int t = (k * (2 * c + 1)) & 1023;
    float v = (k == 0) ? 1.0f : 2.0f * cosf((float)t * (float)(M_PI / 512.0));
    coef[idx] = f2bf(v);
}

__device__ __forceinline__ void gload_lds16(const void* g, void* l) {
    __builtin_amdgcn_global_load_lds(
        (const __attribute__((address_space(1))) unsigned int*)g,
        (__attribute__((address_space(3))) unsigned int*)l,
        16, 0, 0);
}

// Rows are 128 B (64 bf16 = one BK window). 8 16-B quads/row, stored at
// slot = j ^ (row & 7)  -> every wave b128 read/write hits each bank-quad
// exactly 8x (the 1024B/wave floor) = conflict-free.

__global__ __launch_bounds__(512, 4)
void dct_gemm(const float* __restrict__ X, const unsigned short* __restrict__ Mcoef,
              float* __restrict__ Out) {
    __shared__ __align__(16) unsigned char lds[81920];

    const int tid  = threadIdx.x;
    const int lane = tid & 63;
    const int wave = tid >> 6;
    const int m16  = lane & 15;
    const int quad = lane >> 4;
    const int wm   = wave >> 1;       // 0..3 -> 64-row c-strip
    const int wn   = wave & 1;        // 0..1 -> 32-col p-half

    const int p0 = blockIdx.x * BN;
    const size_t bbase = (size_t)blockIdx.z * (NC * NHW);
    const float* Xg = X + bbase;
    float* Og = Out + bbase;

    // ---- A staging: 4x global_load_lds per thread per k-step (linear LDS dest,
    //      pre-swizzled global source). instr i covers rows i*64 + tid/8. ----
    const int trow = tid >> 3;                       // 0..63
    const int tj   = (tid & 7) ^ (trow & 7);         // logical quad stored at this slot
    const unsigned short* aS = Mcoef + trow * NC + tj * 8;
    const int aDst = tid * 16;                       // + i*8192 + buf

    // ---- X staging: thread: p = tid&63, k-chunk = wave*8 (8 floats -> 16 B) ----
    const int sp = tid & 63;
    const float* xSrc = Xg + (size_t)(wave * 8) * NHW + p0 + sp;
    const int xWoff = sp * 128 + ((wave ^ (sp & 7)) << 4);   // swizzled b128 slot

    // ---- loop-invariant swizzled fragment byte offsets ----
    int offA[4][2], offB[2][2];
#pragma unroll
    for (int mt = 0; mt < 4; mt++) {
        const int r = wm * 64 + mt * 16 + m16;
#pragma unroll
        for (int kk = 0; kk < 2; kk++)
            offA[mt][kk] = (r << 7) + (((kk * 4 + quad) ^ (m16 & 7)) << 4);
    }
#pragma unroll
    for (int nt = 0; nt < 2; nt++) {
        const int r = wn * 32 + nt * 16 + m16;
#pragma unroll
        for (int kk = 0; kk < 2; kk++)
            offB[nt][kk] = XBASE + (r << 7) + (((kk * 4 + quad) ^ (m16 & 7)) << 4);
    }

    f32x4 acc[4][2];
#pragma unroll
    for (int i = 0; i < 4; i++)
#pragma unroll
        for (int j = 0; j < 2; j++) acc[i][j] = (f32x4){0.f, 0.f, 0.f, 0.f};

    // ---- prologue: stage tile 0 into buffer 0 ----
    {
        float xv[8];
#pragma unroll
        for (int j = 0; j < 8; j++) xv[j] = xSrc[(size_t)j * NHW];  // 64 lanes = 256 B coalesced
#pragma unroll
        for (int i = 0; i < 4; i++)
            gload_lds16(aS + i * 64 * NC, lds + i * 8192 + aDst);
        int4 w = { (int)pack2bf(xv[0], xv[1]), (int)pack2bf(xv[2], xv[3]),
                   (int)pack2bf(xv[4], xv[5]), (int)pack2bf(xv[6], xv[7]) };
        *(int4*)(lds + XBASE + xWoff) = w;
    }
    __syncthreads();

    // ---- main loop: 1 barrier per k-step, depth-1 prefetch ----
#pragma unroll
    for (int t = 0; t < NITER; t++) {
        const int cb = t & 1;
        const unsigned char* Ac = lds + cb * 32768;
        const unsigned char* Xc = lds + cb * 8192;          // + XBASE via offB
        unsigned char* As = lds + (cb ^ 1) * 32768;
        unsigned char* Xs = lds + XBASE + (cb ^ 1) * 8192;

        float xv[8];
        if (t + 1 < NITER) {
            const int k0 = (t + 1) * BK;
            // X reg-loads first, then async A global->LDS: the pre-ds_write wait
            // can then leave the A gloads in flight under the MFMA phase.
#pragma unroll
            for (int j = 0; j < 8; j++) xv[j] = xSrc[(size_t)(k0 + j) * NHW];
#pragma unroll
            for (int i = 0; i < 4; i++)
                gload_lds16(aS + i * 64 * NC + k0, As + i * 8192 + aDst);
        }

#pragma unroll
        for (int kk = 0; kk < 2; kk++) {
            bf16x8 af[4], bfr[2];
#pragma unroll
            for (int mt = 0; mt < 4; mt++) af[mt] = *(const bf16x8*)(Ac + offA[mt][kk]);
#pragma unroll
            for (int nt = 0; nt < 2; nt++) bfr[nt] = *(const bf16x8*)(Xc + offB[nt][kk]);
#pragma unroll
            for (int mt = 0; mt < 4; mt++)
#pragma unroll
                for (int nt = 0; nt < 2; nt++)
                    acc[mt][nt] = __builtin_amdgcn_mfma_f32_16x16x32_bf16(
                        af[mt], bfr[nt], acc[mt][nt], 0, 0, 0);
        }

        if (t + 1 < NITER) {
            int4 w = { (int)pack2bf(xv[0], xv[1]), (int)pack2bf(xv[2], xv[3]),
                       (int)pack2bf(xv[4], xv[5]), (int)pack2bf(xv[6], xv[7]) };
            *(int4*)(Xs + xWoff) = w;
            __syncthreads();   // drains gload_lds + makes ds_write visible
        }
    }

    // ---- epilogue: D layout col(p) = lane&15, row(c) = quad*4 + r; plain stores
    //      (nontemporal caused +23% WRITE_SIZE via partial-line streaming) ----
#pragma unroll
    for (int mt = 0; mt < 4; mt++) {
        const int cc = wm * 64 + mt * 16 + quad * 4;
#pragma unroll
        for (int nt = 0; nt < 2; nt++) {
            const int pp = p0 + wn * 32 + nt * 16 + m16;
            float* o = Og + (size_t)cc * NHW + pp;
#pragma unroll
            for (int r = 0; r < 4; r++)
                o[(size_t)r * NHW] = acc[mt][nt][r];
        }
    }
}

extern "C" void kernel_launch(void* const* d_in, const int* in_sizes, int n_in,
                              void* d_out, int out_size, void* d_ws, size_t ws_size,
                              hipStream_t stream) {
    const float* ip = (const float*)d_in[0];
    float* out = (float*)d_out;
    unsigned short* coef = (unsigned short*)d_ws;   // 256*256*2 = 128 KB of scratch

    // must redo every launch: d_ws is re-poisoned before each timed call
    coef_kernel<<<dim3(256), dim3(256), 0, stream>>>(coef);

    dim3 grid(NHW / BN, 1, NB);   // (256, 1, 8)
    dct_gemm<<<grid, dim3(512), 0, stream>>>(ip, coef, out);
}